// Round 1
// baseline (392.961 us; speedup 1.0000x reference)
//
#include <hip/hip_runtime.h>

#define NF      100
#define BLOCK   64                  // ONE wave per block: zero cross-wave coupling
#define TILE    64                  // rows per tile; one row per lane
#define F4T     (TILE * 25)         // 1600 float4 = exactly 25 per lane (no padding)
#define NLD     25                  // staging issues per wave, exact -> no over-fetch
#define NBUF    3
#define MAXGRID 512                 // 2 blocks/CU; LDS = 3*25.6 + 0.8 = 77.6 KiB

// Wave-uniform staging: every wave issues exactly NLD global_load_lds per tile.
// Per-lane SOURCE clamped in range; DEST = base + lane*16, linear (HW requirement).
__device__ __forceinline__ void stage_tile(const float4* __restrict__ x4,
                                           float4* dst, int f4base, int maxf4,
                                           int tid) {
#pragma unroll
  for (int u = 0; u < NLD; ++u) {
    int g = f4base + u * BLOCK + tid;
    g = g > maxf4 ? maxf4 : g;       // only bites on the final partial tile / dummy stages
    __builtin_amdgcn_global_load_lds(
        (const __attribute__((address_space(1))) void*)(x4 + g),
        (__attribute__((address_space(3))) void*)(dst + u * BLOCK + tid),
        16, 0, 0);
  }
}

// s_waitcnt imm: vmcnt[3:0]@[3:0], expcnt@[6:4], lgkmcnt@[11:8], vmcnt[5:4]@[15:14]
// 0x4F7A = vmcnt(26), expcnt(7)=no-wait, lgkmcnt(15)=no-wait.
// Steady FIFO at loop top: [S_k(25), store_{k-2}(1), S_{k+1}(25), store_{k-1}(1)] = 52
// -> draining to 26 retires exactly S_k (+ the 2-old store); S_{k+1} stays in flight.
// Max outstanding 52 <= 63 (vmcnt width). First two iterations enter with 0 / 26
// outstanding (the pre-loop __syncthreads fully drains S_0,S_1), so the wait is a
// no-op there and the steady pattern starts at iteration 2.
#define WAITCNT_VM26 0x4F7A

__global__ __launch_bounds__(BLOCK, 1) void fused_kernel(
    const float4* __restrict__ x4,
    const float* __restrict__ A_real, const float* __restrict__ A_imag,
    const float* __restrict__ psi_real, const float* __restrict__ psi_imag,
    float2* __restrict__ out, int batch, int ntiles) {
  __shared__ float4 xs[NBUF][F4T];           // 76.8 KiB, linear (global_load_lds dest)
  __shared__ __align__(16) float2 msl[NF];   // (M_re[0,a], M_re[1,a]) per feature

  const int tid = threadIdx.x;               // == lane (one wave per block)
  const int maxf4 = batch * 25 - 1;
  const int stride = gridDim.x;

  float4* b0 = &xs[0][0];
  float4* b1 = &xs[1][0];
  float4* b2 = &xs[2][0];

  // Start the x stream IMMEDIATELY so HBM is busy while the A-phase runs.
  int t = blockIdx.x;
  stage_tile(x4, b0, t * F4T, maxf4, tid);             // tile t
  stage_tile(x4, b1, (t + stride) * F4T, maxf4, tid);  // tile t+stride

  // ---- Phase 1 (per-block, redundant, L2-hot): lane a computes M[:,a];
  // lanes 0..35 also cover feature a+64.
  {
    float pr[10], pi[10];
#pragma unroll
    for (int i = 0; i < 10; ++i) { pr[i] = psi_real[i]; pi[i] = psi_imag[i]; }
    const bool two = tid < (NF - BLOCK);     // 36 lanes take a second feature
    float m0 = 0.f, m1 = 0.f, n0 = 0.f, n1 = 0.f;
#pragma unroll
    for (int i = 0; i < 10; ++i) {
#pragma unroll
      for (int j = 0; j < 10; ++j) {
        float pre = pr[i] * pr[j] + pi[i] * pi[j];
        float pim = pr[i] * pi[j] - pi[i] * pr[j];
        int off = (i * 10 + j) * NF + tid;          // k=0, feature tid
        m0 = fmaf(pre, A_real[off], m0);
        m0 = fmaf(-pim, A_imag[off], m0);
        m1 = fmaf(pre, A_real[off + 10000], m1);    // k=1
        m1 = fmaf(-pim, A_imag[off + 10000], m1);
        if (two) {
          n0 = fmaf(pre, A_real[off + BLOCK], n0);  // feature tid+64
          n0 = fmaf(-pim, A_imag[off + BLOCK], n0);
          n1 = fmaf(pre, A_real[off + BLOCK + 10000], n1);
          n1 = fmaf(-pim, A_imag[off + BLOCK + 10000], n1);
        }
      }
    }
    msl[tid] = make_float2(m0, m1);
    if (two) msl[tid + BLOCK] = make_float2(n0, n1);
  }
  // One-time full drain (vmcnt(0)+lgkmcnt(0) implied): S_0, S_1 land here (issued
  // at cycle ~0, latency hidden under the A-phase) and the msl writes are fenced
  // for the wave-uniform broadcast read below.
  __syncthreads();

  // ---- Entire M into registers: 50 float4 = 200 VGPR. Static indexing only
  // (no scratch), and at 2 blocks/CU we run 1 wave/SIMD with the full 512-VGPR
  // budget, so this cannot spill or cost occupancy we were using.
  const float4* msl4 = (const float4*)msl;
  float4 mreg[50];
#pragma unroll
  for (int j = 0; j < 50; ++j) mreg[j] = msl4[j];

  // ---- Phase 2: persistent, triple-buffered, barrier-free (single-wave) stream.
  for (; t < ntiles; t += stride) {
    __builtin_amdgcn_s_waitcnt(WAITCNT_VM26);  // retire exactly this tile's stage
    __builtin_amdgcn_s_barrier();              // 1-wave: free; acts as LDS fence

    stage_tile(x4, b2, (t + 2 * stride) * F4T, maxf4, tid);  // reuse oldest buf
    // (OOB tiles stage uniformly with clamped source -> same 1 line broadcast;
    //  keeps the vmcnt FIFO arithmetic exact through the epilogue.)

    const float4* xrow = b0 + tid * 25;        // full row per lane
    float a0 = 0.f, a1 = 0.f;
#pragma unroll
    for (int j = 0; j < 25; ++j) {
      float4 xv = xrow[j];                     // ds_read_b128 (8-way bank alias:
      float4 mA = mreg[2 * j];                 //  ~1 kcyc/tile, hidden under the
      float4 mB = mreg[2 * j + 1];             //  ~5 kcyc memory period)
      a0 = fmaf(xv.x, mA.x, a0); a1 = fmaf(xv.x, mA.y, a1);
      a0 = fmaf(xv.y, mA.z, a0); a1 = fmaf(xv.y, mA.w, a1);
      a0 = fmaf(xv.z, mB.x, a0); a1 = fmaf(xv.z, mB.y, a1);
      a0 = fmaf(xv.w, mB.z, a0); a1 = fmaf(xv.w, mB.w, a1);
    }
    const int t0 = t * TILE;
    if (tid < batch - t0) out[t0 + tid] = make_float2(a0, a1);  // 512 B coalesced;
    // every tile has >=32 valid rows, so the store instruction always issues and
    // the vmcnt count stays uniform.

    float4* tmp = b0; b0 = b1; b1 = b2; b2 = tmp;
  }
}

extern "C" void kernel_launch(void* const* d_in, const int* in_sizes, int n_in,
                              void* d_out, int out_size, void* d_ws, size_t ws_size,
                              hipStream_t stream) {
  const float* x  = (const float*)d_in[0];
  const float* Ar = (const float*)d_in[1];
  const float* Ai = (const float*)d_in[2];
  const float* pr = (const float*)d_in[3];
  const float* pi = (const float*)d_in[4];
  const int batch = in_sizes[0] / NF;

  const int ntiles = (batch + TILE - 1) / TILE;
  const int grid = ntiles < MAXGRID ? ntiles : MAXGRID;
  fused_kernel<<<grid, BLOCK, 0, stream>>>(
      (const float4*)x, Ar, Ai, pr, pi, (float2*)d_out, batch, ntiles);
}